// Round 4
// baseline (513.090 us; speedup 1.0000x reference)
//
#include <hip/hip_runtime.h>

#define N_ 16
#define T_ 8
#define L_ 197
#define H_ 12
#define D_ 64
#define Q_ 196
#define C_ 768
#define KP 224          // padded K/pos dimension (7 x 32)
#define ENT 1792        // 8 dchunks * 224 pos, 16B entries per (nt,h) plane
#define ATS 216         // attn epilogue LDS row stride (ushorts, 16B-aligned rows)

typedef unsigned short ushort_t;
typedef __bf16 bf16x8 __attribute__((ext_vector_type(8)));
typedef float floatx4 __attribute__((ext_vector_type(4)));

static __device__ inline ushort_t f2bf(float x) {
  unsigned int u = __float_as_uint(x);
  u += 0x7fffu + ((u >> 16) & 1u);       // RNE
  return (ushort_t)(u >> 16);
}
static __device__ inline unsigned int pack2(float a, float b) {
  return (unsigned int)f2bf(a) | ((unsigned int)f2bf(b) << 16);
}

// ------------- Pass 0: q,k fp32 -> bf16 planes [nt][h][dc 8][pos 224] ------
// grid (128 nt, 7 pos-chunks of 28, 2 inputs), block 256.
// Coalesced float4 reads -> LDS transpose -> uint4 writes in 448B runs.
__global__ __launch_bounds__(256) void convert_kernel(
    const float* __restrict__ q, const float* __restrict__ k,
    uint4* __restrict__ qb, uint4* __restrict__ kb) {
  const int nt  = blockIdx.x;      // 0..127
  const int pc  = blockIdx.y;      // 0..6
  const int inp = blockIdx.z;      // 0 = q, 1 = k
  const int tid = threadIdx.x;
  const int pos0 = pc * 28;

  const float* src = inp ? k : q;
  const float sc = inp ? 1.f : 0.125f;
  uint4* dst = inp ? kb : qb;

  __shared__ uint2 lds[28][194];   // [pos][d-chunk of 4 as packed bf16], 43.5 KB

  // read: 28 rows x 192 float4, fully coalesced
  #pragma unroll
  for (int r = 0; r < 21; r++) {
    int e = tid + 256 * r;                 // < 5376
    int row = e / 192, col = e - row * 192;
    float4 v = *(const float4*)(src + ((size_t)nt * L_ + 1 + pos0 + row) * (H_ * D_) + col * 4);
    uint2 p;
    p.x = pack2(v.x * sc, v.y * sc);
    p.y = pack2(v.z * sc, v.w * sc);
    lds[row][col] = p;
  }
  __syncthreads();

  // write: 96 (h,dc) x 28 pos uint4 entries = 2688
  #pragma unroll
  for (int r = 0; r < 11; r++) {
    int e = tid + 256 * r;
    if (e < 2688) {
      int hd = e / 28, p = e - hd * 28;    // hd = h*8+dc
      uint2 a = lds[p][hd * 2];
      uint2 b = lds[p][hd * 2 + 1];
      int h = hd >> 3, dc = hd & 7;
      uint4 o; o.x = a.x; o.y = a.y; o.z = b.x; o.w = b.y;
      dst[((size_t)nt * H_ + h) * ENT + dc * KP + pos0 + p] = o;
    }
  }
}

// ------------- Stage 1: A[qi][nt][k] = mean_h softmax_k(QK^T/8), bf16 ------
// 1D grid 896, XCD-swizzled so the 4 blocks sharing a K plane land on one XCD.
__global__ __launch_bounds__(256) void attn_kernel(
    const uint4* __restrict__ qb, const uint4* __restrict__ kb,
    ushort_t* __restrict__ A1, ushort_t* __restrict__ A2) {
  const int lin  = blockIdx.x;          // 0..895
  const int xcd  = lin & 7;
  const int slot = lin >> 3;            // 0..111
  const int g    = (slot >> 2) * 8 + xcd;   // K-group 0..223 = (half,nt)
  const int b    = slot & 3;            // q-row block of 64
  const int half = g / 112;
  const int nt   = g - half * 112;
  const int n  = nt / 7, tp = nt % 7;
  const int tq = (half == 0) ? tp + 1 : tp;
  const int tk = (half == 0) ? tp     : tp + 1;
  const int ntq = n * T_ + tq;
  const int ntk = n * T_ + tk;

  const uint4* qpl = qb + (size_t)ntq * H_ * ENT;
  const uint4* kpl = kb + (size_t)ntk * H_ * ENT;
  ushort_t* Ah = (half == 0) ? A1 : A2;

  __shared__ __align__(16) char smem[ENT * 16];   // 28 KB, dual-use
  uint4* ks = (uint4*)smem;            // [dc 8][ki 224] during head loop
  ushort_t* at = (ushort_t*)smem;      // [64][ATS] during epilogue

  const int tid  = threadIdx.x;
  const int lane = tid & 63;
  const int wv   = tid >> 6;
  const int quad = lane >> 4;
  const int l15  = lane & 15;
  const int qi_b = 64 * b + 16 * wv;

  float accA[13][4];
  #pragma unroll
  for (int t = 0; t < 13; t++)
    #pragma unroll
    for (int r = 0; r < 4; r++) accA[t][r] = 0.f;

  uint4 kreg[7];
  #pragma unroll
  for (int r = 0; r < 7; r++) kreg[r] = kpl[tid + 256 * r];

  for (int h = 0; h < H_; h++) {
    __syncthreads();
    #pragma unroll
    for (int r = 0; r < 7; r++) ks[tid + 256 * r] = kreg[r];
    if (h + 1 < H_) {
      #pragma unroll
      for (int r = 0; r < 7; r++) kreg[r] = kpl[(size_t)(h + 1) * ENT + tid + 256 * r];
    }
    bf16x8 qf[2];
    #pragma unroll
    for (int kk = 0; kk < 2; kk++)
      qf[kk] = *(const bf16x8*)&qpl[(size_t)h * ENT + (quad + 4 * kk) * KP + qi_b + l15];
    __syncthreads();

    floatx4 S[13];
    #pragma unroll
    for (int t = 0; t < 13; t++) S[t] = (floatx4){0.f, 0.f, 0.f, 0.f};
    #pragma unroll
    for (int kk = 0; kk < 2; kk++)
      #pragma unroll
      for (int t = 0; t < 13; t++) {
        bf16x8 bbv = *(const bf16x8*)&ks[(quad + 4 * kk) * KP + 16 * t + l15];
        S[t] = __builtin_amdgcn_mfma_f32_16x16x32_bf16(qf[kk], bbv, S[t], 0, 0, 0);
      }

    #pragma unroll
    for (int r = 0; r < 4; r++) {
      float s = 0.f;
      #pragma unroll
      for (int t = 0; t < 13; t++) {
        float e_ = (t == 12 && l15 >= 4) ? 0.f : __expf(S[t][r]);
        S[t][r] = e_;
        s += e_;
      }
      #pragma unroll
      for (int off = 1; off < 16; off <<= 1) s += __shfl_xor(s, off);
      float inv = 1.f / s;
      #pragma unroll
      for (int t = 0; t < 13; t++) accA[t][r] += S[t][r] * inv;
    }
  }

  // epilogue: transpose accA via LDS, store as uint4 (416B runs per row)
  __syncthreads();                     // everyone done with ks
  const float s12 = 1.f / 12.f;
  #pragma unroll
  for (int t = 0; t < 13; t++)
    #pragma unroll
    for (int r = 0; r < 4; r++)
      at[(16 * wv + 4 * quad + r) * ATS + 16 * t + l15] = f2bf(accA[t][r] * s12);
  // wave-private readback (rows 16wv..16wv+15 written by this wave only)
  #pragma unroll
  for (int i = 0; i < 7; i++) {
    int e = lane + 64 * i;             // 16 rows x 26 uint4 = 416
    if (e < 416) {
      int row = e / 26, col = e - row * 26;
      uint4 v = *(const uint4*)&at[(16 * wv + row) * ATS + col * 8];
      int qi = qi_b + row;
      if (qi < Q_)
        *(uint4*)(Ah + ((size_t)qi * (N_ * T_) + ntq) * KP + col * 8) = v;
    }
  }
}

// ------------- Stage 2: out[nt,qi,c] = sum_half A_h[qi] @ gather(W_h) ------
// grid (6 c-tiles of 128, 196 qi), block 256; idx in LDS, reg-prefetch dbuf.
__global__ __launch_bounds__(256) void mix_kernel(
    const ushort_t* __restrict__ A1, const ushort_t* __restrict__ A2,
    const float* __restrict__ w1, const float* __restrict__ w2,
    const int* __restrict__ idx, float* __restrict__ out) {
  const int ct = blockIdx.x;   // 0..5
  const int qi = blockIdx.y;   // 0..195
  const int tid  = threadIdx.x;
  const int lane = tid & 63;
  const int wv   = tid >> 6;
  const int quad = lane >> 4;
  const int l15  = lane & 15;

  __shared__ ushort_t As[128][40];
  __shared__ ushort_t Ws[128][40];
  __shared__ int idx_s[Q_];

  if (tid < Q_) idx_s[tid] = idx[qi * Q_ + tid];

  floatx4 acc[8][2];
  #pragma unroll
  for (int mt = 0; mt < 8; mt++)
    #pragma unroll
    for (int u = 0; u < 2; u++) acc[mt][u] = (floatx4){0.f, 0.f, 0.f, 0.f};

  uint4 pA[2];
  float4 pW[2][2];

  __syncthreads();                     // idx_s ready

  // prefetch chunk (half, kc)
  #define PREFETCH(HALF, KC)                                                     \
    {                                                                            \
      const ushort_t* Ah_ = (HALF) ? A2 : A1;                                    \
      const float* w_ = (HALF) ? w2 : w1;                                        \
      const int k0_ = 32 * (KC);                                                 \
      _Pragma("unroll")                                                          \
      for (int r = 0; r < 2; r++) {                                              \
        int e = tid + 256 * r;                                                   \
        int row = e >> 2, ch = e & 3;                                            \
        pA[r] = *(const uint4*)(Ah_ + ((size_t)qi * (N_ * T_) + row) * KP + k0_ + ch * 8); \
        int cc = e >> 4, kk2 = e & 15;                                           \
        int gk0 = k0_ + 2 * kk2, gk1 = gk0 + 1;                                  \
        float4 z = make_float4(0.f, 0.f, 0.f, 0.f);                              \
        pW[r][0] = (gk0 < Q_) ? *(const float4*)(w_ + (size_t)idx_s[gk0] * C_ + ct * 128 + cc * 4) : z; \
        pW[r][1] = (gk1 < Q_) ? *(const float4*)(w_ + (size_t)idx_s[gk1] * C_ + ct * 128 + cc * 4) : z; \
      }                                                                          \
    }

  PREFETCH(0, 0);

  for (int ht = 0; ht < 14; ht++) {
    __syncthreads();                   // consumers done with LDS
    // commit prefetched tile
    #pragma unroll
    for (int r = 0; r < 2; r++) {
      int e = tid + 256 * r;
      int row = e >> 2, ch = e & 3;
      *(uint4*)&As[row][ch * 8] = pA[r];
    }
    #pragma unroll
    for (int r = 0; r < 2; r++) {
      int e = tid + 256 * r;
      int cc = e >> 4, kk2 = e & 15;
      float4 v0 = pW[r][0], v1 = pW[r][1];
      *(unsigned int*)&Ws[cc * 4 + 0][2 * kk2] = pack2(v0.x, v1.x);
      *(unsigned int*)&Ws[cc * 4 + 1][2 * kk2] = pack2(v0.y, v1.y);
      *(unsigned int*)&Ws[cc * 4 + 2][2 * kk2] = pack2(v0.z, v1.z);
      *(unsigned int*)&Ws[cc * 4 + 3][2 * kk2] = pack2(v0.w, v1.w);
    }
    // issue next prefetch (latency hidden under MFMA phase)
    if (ht + 1 < 14) {
      int nh = (ht + 1) / 7, nk = (ht + 1) % 7;
      PREFETCH(nh, nk);
    }
    __syncthreads();                   // tile ready

    bf16x8 bfv[2];
    #pragma unroll
    for (int u = 0; u < 2; u++)
      bfv[u] = *(const bf16x8*)&Ws[32 * wv + 16 * u + l15][8 * quad];
    #pragma unroll
    for (int mt = 0; mt < 8; mt++) {
      bf16x8 a = *(const bf16x8*)&As[16 * mt + l15][8 * quad];
      acc[mt][0] = __builtin_amdgcn_mfma_f32_16x16x32_bf16(a, bfv[0], acc[mt][0], 0, 0, 0);
      acc[mt][1] = __builtin_amdgcn_mfma_f32_16x16x32_bf16(a, bfv[1], acc[mt][1], 0, 0, 0);
    }
  }

  #pragma unroll
  for (int u = 0; u < 2; u++) {
    const int c = ct * 128 + 32 * wv + 16 * u + l15;
    #pragma unroll
    for (int mt = 0; mt < 8; mt++)
      #pragma unroll
      for (int r = 0; r < 4; r++) {
        int m = 16 * mt + 4 * quad + r;
        out[((size_t)m * L_ + 1 + qi) * C_ + c] = acc[mt][u][r];
      }
  }
  if (qi == 0) {
    #pragma unroll
    for (int u = 0; u < 2; u++) {
      const int c = ct * 128 + 32 * wv + 16 * u + l15;
      #pragma unroll
      for (int mt = 0; mt < 8; mt++)
        #pragma unroll
        for (int r = 0; r < 4; r++) {
          int m = 16 * mt + 4 * quad + r;
          out[(size_t)m * L_ * C_ + c] = 0.f;
        }
    }
  }
}

extern "C" void kernel_launch(void* const* d_in, const int* in_sizes, int n_in,
                              void* d_out, int out_size, void* d_ws, size_t ws_size,
                              hipStream_t stream) {
  const float* q  = (const float*)d_in[0];
  const float* k  = (const float*)d_in[1];
  const float* w1 = (const float*)d_in[2];
  const float* w2 = (const float*)d_in[3];
  const int* idx  = (const int*)d_in[4];
  float* out = (float*)d_out;

  const size_t plane_tot = (size_t)(N_ * T_) * H_ * ENT;   // uint4 entries
  uint4* qb = (uint4*)d_ws;
  uint4* kb = qb + plane_tot;
  ushort_t* A1 = (ushort_t*)(kb + plane_tot);
  size_t Aelems = (size_t)Q_ * (N_ * T_) * KP;
  ushort_t* A2 = A1 + Aelems;

  // zero A buffers: covers k-pad cols and the empty t-slots
  hipMemsetAsync(A1, 0, Aelems * 2 * sizeof(ushort_t), stream);

  convert_kernel<<<dim3(N_ * T_, 7, 2), 256, 0, stream>>>(q, k, qb, kb);
  attn_kernel<<<dim3(896), 256, 0, stream>>>(qb, kb, A1, A2);
  mix_kernel<<<dim3(6, Q_), 256, 0, stream>>>(A1, A2, w1, w2, idx, out);
}

// Round 5
// 450.640 us; speedup vs baseline: 1.1386x; 1.1386x over previous
//
#include <hip/hip_runtime.h>

#define N_ 16
#define T_ 8
#define L_ 197
#define H_ 12
#define D_ 64
#define Q_ 196
#define C_ 768
#define KP 224          // padded K/pos dimension (7 x 32)
#define ENT 1792        // 8 dchunks * 224 pos, 16B entries per (nt,h) plane
#define ATS 216         // attn epilogue LDS row stride (ushorts, 16B-aligned rows)

typedef unsigned short ushort_t;
typedef __bf16 bf16x8 __attribute__((ext_vector_type(8)));
typedef float floatx4 __attribute__((ext_vector_type(4)));

static __device__ inline ushort_t f2bf(float x) {
  unsigned int u = __float_as_uint(x);
  u += 0x7fffu + ((u >> 16) & 1u);       // RNE
  return (ushort_t)(u >> 16);
}
static __device__ inline unsigned int pack2(float a, float b) {
  return (unsigned int)f2bf(a) | ((unsigned int)f2bf(b) << 16);
}

// ------------- Pass 0: q,k fp32 -> bf16 planes [nt][h][dc 8][pos 224] ------
// grid (128 nt, 7 pos-chunks of 28, 2 inputs), block 256.
// Coalesced float4 reads -> LDS transpose -> uint4 writes in 448B runs.
__global__ __launch_bounds__(256) void convert_kernel(
    const float* __restrict__ q, const float* __restrict__ k,
    uint4* __restrict__ qb, uint4* __restrict__ kb) {
  const int nt  = blockIdx.x;      // 0..127
  const int pc  = blockIdx.y;      // 0..6
  const int inp = blockIdx.z;      // 0 = q, 1 = k
  const int tid = threadIdx.x;
  const int pos0 = pc * 28;

  const float* src = inp ? k : q;
  const float sc = inp ? 1.f : 0.125f;
  uint4* dst = inp ? kb : qb;

  __shared__ uint2 lds[28][194];   // [pos][d-chunk of 4 as packed bf16], 43.5 KB

  #pragma unroll
  for (int r = 0; r < 21; r++) {
    int e = tid + 256 * r;                 // < 5376
    int row = e / 192, col = e - row * 192;
    float4 v = *(const float4*)(src + ((size_t)nt * L_ + 1 + pos0 + row) * (H_ * D_) + col * 4);
    uint2 p;
    p.x = pack2(v.x * sc, v.y * sc);
    p.y = pack2(v.z * sc, v.w * sc);
    lds[row][col] = p;
  }
  __syncthreads();

  #pragma unroll
  for (int r = 0; r < 11; r++) {
    int e = tid + 256 * r;
    if (e < 2688) {
      int hd = e / 28, p = e - hd * 28;    // hd = h*8+dc
      uint2 a = lds[p][hd * 2];
      uint2 b = lds[p][hd * 2 + 1];
      int h = hd >> 3, dc = hd & 7;
      uint4 o; o.x = a.x; o.y = a.y; o.z = b.x; o.w = b.y;
      dst[((size_t)nt * H_ + h) * ENT + dc * KP + pos0 + p] = o;
    }
  }
}

// ------------- Stage 1: A[qi][nt][k] = mean_h softmax_k(QK^T/8), bf16 ------
// 1D grid 896, XCD-swizzled so the 4 blocks sharing a K plane land on one XCD.
// K plane AND Q frags double-buffered in registers: MFMA never waits on vmem.
__global__ __launch_bounds__(256) void attn_kernel(
    const uint4* __restrict__ qb, const uint4* __restrict__ kb,
    ushort_t* __restrict__ A1, ushort_t* __restrict__ A2) {
  const int lin  = blockIdx.x;          // 0..895
  const int xcd  = lin & 7;
  const int slot = lin >> 3;            // 0..111
  const int g    = (slot >> 2) * 8 + xcd;   // K-group 0..223 = (half,nt)
  const int b    = slot & 3;            // q-row block of 64
  const int half = g / 112;
  const int nt   = g - half * 112;
  const int n  = nt / 7, tp = nt % 7;
  const int tq = (half == 0) ? tp + 1 : tp;
  const int tk = (half == 0) ? tp     : tp + 1;
  const int ntq = n * T_ + tq;
  const int ntk = n * T_ + tk;

  const uint4* qpl = qb + (size_t)ntq * H_ * ENT;
  const uint4* kpl = kb + (size_t)ntk * H_ * ENT;
  ushort_t* Ah = (half == 0) ? A1 : A2;

  __shared__ __align__(16) char smem[ENT * 16];   // 28 KB, dual-use
  uint4* ks = (uint4*)smem;            // [dc 8][ki 224] during head loop
  ushort_t* at = (ushort_t*)smem;      // [64][ATS] during epilogue

  const int tid  = threadIdx.x;
  const int lane = tid & 63;
  const int wv   = tid >> 6;
  const int quad = lane >> 4;
  const int l15  = lane & 15;
  const int qi_b = 64 * b + 16 * wv;

  float accA[13][4];
  #pragma unroll
  for (int t = 0; t < 13; t++)
    #pragma unroll
    for (int r = 0; r < 4; r++) accA[t][r] = 0.f;

  // preload head 0: K plane + Q frags
  uint4 kreg[7];
  #pragma unroll
  for (int r = 0; r < 7; r++) kreg[r] = kpl[tid + 256 * r];
  bf16x8 qf[2], qfn[2];
  #pragma unroll
  for (int kk = 0; kk < 2; kk++) {
    qf[kk] = *(const bf16x8*)&qpl[(quad + 4 * kk) * KP + qi_b + l15];
    qfn[kk] = qf[kk];
  }

  for (int h = 0; h < H_; h++) {
    __syncthreads();                 // all waves done reading ks (prev head)
    #pragma unroll
    for (int r = 0; r < 7; r++) ks[tid + 256 * r] = kreg[r];
    // prefetch next head's K plane AND Q frags (consumed next iteration)
    if (h + 1 < H_) {
      #pragma unroll
      for (int r = 0; r < 7; r++) kreg[r] = kpl[(size_t)(h + 1) * ENT + tid + 256 * r];
      #pragma unroll
      for (int kk = 0; kk < 2; kk++)
        qfn[kk] = *(const bf16x8*)&qpl[(size_t)(h + 1) * ENT + (quad + 4 * kk) * KP + qi_b + l15];
    }
    __syncthreads();                 // ks ready

    floatx4 S[13];
    #pragma unroll
    for (int t = 0; t < 13; t++) S[t] = (floatx4){0.f, 0.f, 0.f, 0.f};
    #pragma unroll
    for (int kk = 0; kk < 2; kk++)
      #pragma unroll
      for (int t = 0; t < 13; t++) {
        bf16x8 bbv = *(const bf16x8*)&ks[(quad + 4 * kk) * KP + 16 * t + l15];
        S[t] = __builtin_amdgcn_mfma_f32_16x16x32_bf16(qf[kk], bbv, S[t], 0, 0, 0);
      }

    #pragma unroll
    for (int r = 0; r < 4; r++) {
      float s = 0.f;
      #pragma unroll
      for (int t = 0; t < 13; t++) {
        float e_ = (t == 12 && l15 >= 4) ? 0.f : __expf(S[t][r]);
        S[t][r] = e_;
        s += e_;
      }
      #pragma unroll
      for (int off = 1; off < 16; off <<= 1) s += __shfl_xor(s, off);
      float inv = 1.f / s;
      #pragma unroll
      for (int t = 0; t < 13; t++) accA[t][r] += S[t][r] * inv;
    }
    qf[0] = qfn[0];
    qf[1] = qfn[1];
  }

  // epilogue: transpose accA via LDS, store as uint4 (416B runs per row)
  __syncthreads();
  const float s12 = 1.f / 12.f;
  #pragma unroll
  for (int t = 0; t < 13; t++)
    #pragma unroll
    for (int r = 0; r < 4; r++)
      at[(16 * wv + 4 * quad + r) * ATS + 16 * t + l15] = f2bf(accA[t][r] * s12);
  #pragma unroll
  for (int i = 0; i < 7; i++) {
    int e = lane + 64 * i;             // 16 rows x 26 uint4 = 416
    if (e < 416) {
      int row = e / 26, col = e - row * 26;
      uint4 v = *(const uint4*)&at[(16 * wv + row) * ATS + col * 8];
      int qi = qi_b + row;
      if (qi < Q_)
        *(uint4*)(Ah + ((size_t)qi * (N_ * T_) + ntq) * KP + col * 8) = v;
    }
  }
}

// ------------- Stage 2: out[nt,qi,c] = sum_half A_h[qi] @ gather(W_h) ------
// grid (6 c-tiles of 128, 196 qi), block 256; idx in REGISTERS, reg-prefetch.
__global__ __launch_bounds__(256) void mix_kernel(
    const ushort_t* __restrict__ A1, const ushort_t* __restrict__ A2,
    const float* __restrict__ w1, const float* __restrict__ w2,
    const int* __restrict__ idx, float* __restrict__ out) {
  const int ct = blockIdx.x;   // 0..5
  const int qi = blockIdx.y;   // 0..195
  const int tid  = threadIdx.x;
  const int lane = tid & 63;
  const int wv   = tid >> 6;
  const int quad = lane >> 4;
  const int l15  = lane & 15;
  const int kk2  = tid & 15;   // this thread's k-pair slot within a 32-chunk

  __shared__ ushort_t As[128][40];
  __shared__ ushort_t Ws[128][40];

  // idx for this thread's gather rows, all 7 k-chunks, loaded once.
  int idxr0[7], idxr1[7];
  #pragma unroll
  for (int kc = 0; kc < 7; kc++) {
    int off = 32 * kc + 2 * kk2;
    if (off > 194) off = 194;          // clamp in-bounds; OOB lanes masked below
    int2 p = *(const int2*)(idx + (size_t)qi * Q_ + off);
    idxr0[kc] = p.x; idxr1[kc] = p.y;
  }

  floatx4 acc[8][2];
  #pragma unroll
  for (int mt = 0; mt < 8; mt++)
    #pragma unroll
    for (int u = 0; u < 2; u++) acc[mt][u] = (floatx4){0.f, 0.f, 0.f, 0.f};

  uint4 pA[2];
  float4 pW[2][2];

  // prefetch chunk (half, kc) — KC must be compile-time (idxr indexing)
  #define PREFETCH(HALF, KC)                                                     \
    {                                                                            \
      const ushort_t* Ah_ = (HALF) ? A2 : A1;                                    \
      const float* w_ = (HALF) ? w2 : w1;                                        \
      const int k0_ = 32 * (KC);                                                 \
      _Pragma("unroll")                                                          \
      for (int r = 0; r < 2; r++) {                                              \
        int e = tid + 256 * r;                                                   \
        int row = e >> 2, ch = e & 3;                                            \
        pA[r] = *(const uint4*)(Ah_ + ((size_t)qi * (N_ * T_) + row) * KP + k0_ + ch * 8); \
        int cc = e >> 4;                                                         \
        int gk0 = k0_ + 2 * kk2, gk1 = gk0 + 1;                                  \
        float4 z = make_float4(0.f, 0.f, 0.f, 0.f);                              \
        pW[r][0] = (gk0 < Q_) ? *(const float4*)(w_ + (size_t)idxr0[KC] * C_ + ct * 128 + cc * 4) : z; \
        pW[r][1] = (gk1 < Q_) ? *(const float4*)(w_ + (size_t)idxr1[KC] * C_ + ct * 128 + cc * 4) : z; \
      }                                                                          \
    }

  PREFETCH(0, 0);

  #pragma unroll
  for (int ht = 0; ht < 14; ht++) {
    __syncthreads();                   // consumers done with LDS
    #pragma unroll
    for (int r = 0; r < 2; r++) {
      int e = tid + 256 * r;
      int row = e >> 2, ch = e & 3;
      *(uint4*)&As[row][ch * 8] = pA[r];
    }
    #pragma unroll
    for (int r = 0; r < 2; r++) {
      int e = tid + 256 * r;
      int cc = e >> 4;
      float4 v0 = pW[r][0], v1 = pW[r][1];
      *(unsigned int*)&Ws[cc * 4 + 0][2 * kk2] = pack2(v0.x, v1.x);
      *(unsigned int*)&Ws[cc * 4 + 1][2 * kk2] = pack2(v0.y, v1.y);
      *(unsigned int*)&Ws[cc * 4 + 2][2 * kk2] = pack2(v0.z, v1.z);
      *(unsigned int*)&Ws[cc * 4 + 3][2 * kk2] = pack2(v0.w, v1.w);
    }
    if (ht + 1 < 14) {
      PREFETCH((ht + 1) / 7, (ht + 1) % 7);   // compile-time after unroll
    }
    __syncthreads();                   // tile ready

    bf16x8 bfv[2];
    #pragma unroll
    for (int u = 0; u < 2; u++)
      bfv[u] = *(const bf16x8*)&Ws[32 * wv + 16 * u + l15][8 * quad];
    #pragma unroll
    for (int mt = 0; mt < 8; mt++) {
      bf16x8 a = *(const bf16x8*)&As[16 * mt + l15][8 * quad];
      acc[mt][0] = __builtin_amdgcn_mfma_f32_16x16x32_bf16(a, bfv[0], acc[mt][0], 0, 0, 0);
      acc[mt][1] = __builtin_amdgcn_mfma_f32_16x16x32_bf16(a, bfv[1], acc[mt][1], 0, 0, 0);
    }
  }

  #pragma unroll
  for (int u = 0; u < 2; u++) {
    const int c = ct * 128 + 32 * wv + 16 * u + l15;
    #pragma unroll
    for (int mt = 0; mt < 8; mt++)
      #pragma unroll
      for (int r = 0; r < 4; r++) {
        int m = 16 * mt + 4 * quad + r;
        out[((size_t)m * L_ + 1 + qi) * C_ + c] = acc[mt][u][r];
      }
  }
  if (qi == 0) {
    #pragma unroll
    for (int u = 0; u < 2; u++) {
      const int c = ct * 128 + 32 * wv + 16 * u + l15;
      #pragma unroll
      for (int mt = 0; mt < 8; mt++)
        #pragma unroll
        for (int r = 0; r < 4; r++) {
          int m = 16 * mt + 4 * quad + r;
          out[(size_t)m * L_ * C_ + c] = 0.f;
        }
    }
  }
}

extern "C" void kernel_launch(void* const* d_in, const int* in_sizes, int n_in,
                              void* d_out, int out_size, void* d_ws, size_t ws_size,
                              hipStream_t stream) {
  const float* q  = (const float*)d_in[0];
  const float* k  = (const float*)d_in[1];
  const float* w1 = (const float*)d_in[2];
  const float* w2 = (const float*)d_in[3];
  const int* idx  = (const int*)d_in[4];
  float* out = (float*)d_out;

  const size_t plane_tot = (size_t)(N_ * T_) * H_ * ENT;   // uint4 entries
  uint4* qb = (uint4*)d_ws;
  uint4* kb = qb + plane_tot;
  ushort_t* A1 = (ushort_t*)(kb + plane_tot);
  size_t Aelems = (size_t)Q_ * (N_ * T_) * KP;
  ushort_t* A2 = A1 + Aelems;

  // zero A buffers: covers k-pad cols and the empty t-slots
  hipMemsetAsync(A1, 0, Aelems * 2 * sizeof(ushort_t), stream);

  convert_kernel<<<dim3(N_ * T_, 7, 2), 256, 0, stream>>>(q, k, qb, kb);
  attn_kernel<<<dim3(896), 256, 0, stream>>>(qb, kb, A1, A2);
  mix_kernel<<<dim3(6, Q_), 256, 0, stream>>>(A1, A2, w1, w2, idx, out);
}

// Round 6
// 406.544 us; speedup vs baseline: 1.2621x; 1.1085x over previous
//
#include <hip/hip_runtime.h>

#define N_ 16
#define T_ 8
#define L_ 197
#define H_ 12
#define D_ 64
#define Q_ 196
#define C_ 768
#define KP 224          // padded K/pos dimension (7 x 32)
#define ENT 1792        // 8 dchunks * 224 pos, 16B entries per (nt,h) plane
#define ATS 216         // attn epilogue LDS row stride (ushorts)
#define APLANE 2112     // mix: As plane stride bytes (2048 + 64 skew)

typedef unsigned short ushort_t;
typedef __bf16 bf16x8 __attribute__((ext_vector_type(8)));
typedef float floatx4 __attribute__((ext_vector_type(4)));

// async global->LDS, 16B per lane, dst = uniform base + lane*16
#define GLD_LDS16(g, l)                                                    \
  __builtin_amdgcn_global_load_lds(                                        \
      (const __attribute__((address_space(1))) void*)(g),                  \
      (__attribute__((address_space(3))) void*)(l), 16, 0, 0)

static __device__ inline ushort_t f2bf(float x) {
  unsigned int u = __float_as_uint(x);
  u += 0x7fffu + ((u >> 16) & 1u);       // RNE
  return (ushort_t)(u >> 16);
}
static __device__ inline unsigned int pack2(float a, float b) {
  return (unsigned int)f2bf(a) | ((unsigned int)f2bf(b) << 16);
}

// ------------- Pass 0: q,k fp32 -> bf16 planes [nt][h][dc 8][pos 224] ------
__global__ __launch_bounds__(256) void convert_kernel(
    const float* __restrict__ q, const float* __restrict__ k,
    uint4* __restrict__ qb, uint4* __restrict__ kb) {
  const int nt  = blockIdx.x;      // 0..127
  const int pc  = blockIdx.y;      // 0..6
  const int inp = blockIdx.z;      // 0 = q, 1 = k
  const int tid = threadIdx.x;
  const int pos0 = pc * 28;

  const float* src = inp ? k : q;
  const float sc = inp ? 1.f : 0.125f;
  uint4* dst = inp ? kb : qb;

  __shared__ uint2 lds[28][194];

  #pragma unroll
  for (int r = 0; r < 21; r++) {
    int e = tid + 256 * r;                 // < 5376
    int row = e / 192, col = e - row * 192;
    float4 v = *(const float4*)(src + ((size_t)nt * L_ + 1 + pos0 + row) * (H_ * D_) + col * 4);
    uint2 p;
    p.x = pack2(v.x * sc, v.y * sc);
    p.y = pack2(v.z * sc, v.w * sc);
    lds[row][col] = p;
  }
  __syncthreads();

  #pragma unroll
  for (int r = 0; r < 11; r++) {
    int e = tid + 256 * r;
    if (e < 2688) {
      int hd = e / 28, p = e - hd * 28;    // hd = h*8+dc
      uint2 a = lds[p][hd * 2];
      uint2 b = lds[p][hd * 2 + 1];
      int h = hd >> 3, dc = hd & 7;
      uint4 o; o.x = a.x; o.y = a.y; o.z = b.x; o.w = b.y;
      dst[((size_t)nt * H_ + h) * ENT + dc * KP + pos0 + p] = o;
    }
  }
}

// ------------- Stage 1: A[qi][nt][k] = mean_h softmax_k(QK^T/8), bf16 ------
// 1D grid 896, XCD-swizzled. K staged via global_load_lds (zero landing regs).
__global__ __launch_bounds__(256, 4) void attn_kernel(
    const uint4* __restrict__ qb, const uint4* __restrict__ kb,
    ushort_t* __restrict__ A1, ushort_t* __restrict__ A2) {
  const int lin  = blockIdx.x;          // 0..895
  const int xcd  = lin & 7;
  const int slot = lin >> 3;            // 0..111
  const int g    = (slot >> 2) * 8 + xcd;   // K-group 0..223
  const int b    = slot & 3;            // q-row block of 64
  const int half = g / 112;
  const int nt   = g - half * 112;
  const int n  = nt / 7, tp = nt % 7;
  const int tq = (half == 0) ? tp + 1 : tp;
  const int tk = (half == 0) ? tp     : tp + 1;
  const int ntq = n * T_ + tq;
  const int ntk = n * T_ + tk;

  const uint4* qpl = qb + (size_t)ntq * H_ * ENT;
  const uint4* kpl = kb + (size_t)ntk * H_ * ENT;
  ushort_t* Ah = (half == 0) ? A1 : A2;

  __shared__ __align__(16) uint4 ks[ENT];   // 28 KB; epilogue alias
  ushort_t* at = (ushort_t*)ks;
  const ushort_t* ksu = (const ushort_t*)ks;

  const int tid  = threadIdx.x;
  const int lane = tid & 63;
  const int wv   = tid >> 6;
  const int quad = lane >> 4;
  const int l15  = lane & 15;
  const int qi_b = 64 * b + 16 * wv;

  float accA[13][4];
  #pragma unroll
  for (int t = 0; t < 13; t++)
    #pragma unroll
    for (int r = 0; r < 4; r++) accA[t][r] = 0.f;

  // head 0: async K DMA + Q frags
  #pragma unroll
  for (int r = 0; r < 7; r++)
    GLD_LDS16(kpl + 256 * r + 64 * wv + lane, (char*)ks + (256 * r + 64 * wv) * 16);
  bf16x8 qf[2];
  #pragma unroll
  for (int kk = 0; kk < 2; kk++)
    qf[kk] = *(const bf16x8*)&qpl[(quad + 4 * kk) * KP + qi_b + l15];

  for (int h = 0; h < H_; h++) {
    __syncthreads();                 // drains DMA(h) + qf(h); ks ready

    floatx4 S[13];
    #pragma unroll
    for (int t = 0; t < 13; t++) S[t] = (floatx4){0.f, 0.f, 0.f, 0.f};
    #pragma unroll
    for (int kk = 0; kk < 2; kk++)
      #pragma unroll
      for (int t = 0; t < 13; t++) {
        bf16x8 bbv = *(const bf16x8*)&ksu[((quad + 4 * kk) * KP + 16 * t + l15) * 8];
        S[t] = __builtin_amdgcn_mfma_f32_16x16x32_bf16(qf[kk], bbv, S[t], 0, 0, 0);
      }

    __syncthreads();                 // all waves done reading ks
    // issue next head's K DMA + Q frags NOW; softmax below overlaps the fetch
    if (h + 1 < H_) {
      #pragma unroll
      for (int kk = 0; kk < 2; kk++)
        qf[kk] = *(const bf16x8*)&qpl[(size_t)(h + 1) * ENT + (quad + 4 * kk) * KP + qi_b + l15];
      #pragma unroll
      for (int r = 0; r < 7; r++)
        GLD_LDS16(kpl + (size_t)(h + 1) * ENT + 256 * r + 64 * wv + lane,
                  (char*)ks + (256 * r + 64 * wv) * 16);
    }

    // softmax over k (196 valid), accumulate P/rowsum (pure VALU — overlaps DMA)
    #pragma unroll
    for (int r = 0; r < 4; r++) {
      float s = 0.f;
      #pragma unroll
      for (int t = 0; t < 13; t++) {
        float e_ = (t == 12 && l15 >= 4) ? 0.f : __expf(S[t][r]);
        S[t][r] = e_;
        s += e_;
      }
      #pragma unroll
      for (int off = 1; off < 16; off <<= 1) s += __shfl_xor(s, off);
      float inv = 1.f / s;
      #pragma unroll
      for (int t = 0; t < 13; t++) accA[t][r] += S[t][r] * inv;
    }
  }

  // epilogue: transpose accA via LDS (wave-private rows), uint4 stores
  const float s12 = 1.f / 12.f;
  #pragma unroll
  for (int t = 0; t < 13; t++)
    #pragma unroll
    for (int r = 0; r < 4; r++)
      at[(16 * wv + 4 * quad + r) * ATS + 16 * t + l15] = f2bf(accA[t][r] * s12);
  #pragma unroll
  for (int i = 0; i < 7; i++) {
    int e = lane + 64 * i;             // 16 rows x 26 uint4 = 416
    if (e < 416) {
      int row = e / 26, col = e - row * 26;
      uint4 v = *(const uint4*)&at[(16 * wv + row) * ATS + col * 8];
      int qi = qi_b + row;
      if (qi < Q_)
        *(uint4*)(Ah + ((size_t)qi * (N_ * T_) + ntq) * KP + col * 8) = v;
    }
  }
}

// ------------- Stage 2: out[nt,qi,c] = sum_half A_h[qi] @ gather(W_h) ------
// grid (6 c-tiles of 128, 196 qi), block 256. As via DMA (dbuf, skewed
// planes); W gather is wave-private -> ONE barrier per chunk.
__global__ __launch_bounds__(256, 4) void mix_kernel(
    const ushort_t* __restrict__ A1, const ushort_t* __restrict__ A2,
    const float* __restrict__ w1, const float* __restrict__ w2,
    const int* __restrict__ idx, float* __restrict__ out) {
  const int ct = blockIdx.x;   // 0..5
  const int qi = blockIdx.y;   // 0..195
  const int tid  = threadIdx.x;
  const int lane = tid & 63;
  const int wv   = tid >> 6;
  const int quad = lane >> 4;
  const int l15  = lane & 15;
  const int p    = lane >> 2;  // k-pair 0..15
  const int cq   = lane & 3;   // c-chunk slot

  __shared__ __align__(16) char As[2][4 * APLANE];   // 2 x 8448 B
  __shared__ ushort_t Ws[128][40];                   // wave-private rows

  // idx regs: this lane's two k-rows per chunk (clamped; A=0 kills pad cols)
  int idxr0[7], idxr1[7];
  #pragma unroll
  for (int kc = 0; kc < 7; kc++) {
    int off = 32 * kc + 2 * p;
    if (off > 194) off = 194;
    int2 pr = *(const int2*)(idx + (size_t)qi * Q_ + off);
    idxr0[kc] = pr.x; idxr1[kc] = pr.y;
  }

  floatx4 acc[8][2];
  #pragma unroll
  for (int mt = 0; mt < 8; mt++)
    #pragma unroll
    for (int u = 0; u < 2; u++) acc[mt][u] = (floatx4){0.f, 0.f, 0.f, 0.f};

  float4 pw[2][2];   // [k-offset j][c-chunk u]
  const int cbase = ct * 128 + wv * 32;

  // ---- preload chunk 0 ----
  {
    const ushort_t* Ah_ = A1;
    #pragma unroll
    for (int r = 0; r < 2; r++)
      GLD_LDS16(Ah_ + ((size_t)qi * 128 + r * 64 + lane) * KP + wv * 8,
                As[0] + wv * APLANE + r * 1024);
    #pragma unroll
    for (int j = 0; j < 2; j++)
      #pragma unroll
      for (int u = 0; u < 2; u++)
        pw[j][u] = *(const float4*)(w1 + (size_t)(j ? idxr1[0] : idxr0[0]) * C_ +
                                    cbase + (cq + 4 * u) * 4);
  }

  #pragma unroll
  for (int ht = 0; ht < 14; ht++) {
    const int half = ht / 7, kc = ht % 7;
    __syncthreads();                 // As[ht&1] DMA + pw gather drained

    // commit this chunk's W (wave-private -> no barrier needed)
    #pragma unroll
    for (int u = 0; u < 2; u++) {
      const float* f0 = (const float*)&pw[0][u];
      const float* f1 = (const float*)&pw[1][u];
      #pragma unroll
      for (int e = 0; e < 4; e++)
        *(unsigned int*)&Ws[wv * 32 + (cq + 4 * u) * 4 + e][2 * p] = pack2(f0[e], f1[e]);
    }

    // issue next chunk's A-DMA + W-gather (in flight through the MFMA phase)
    if (ht + 1 < 14) {
      const int nh = (ht + 1) / 7, nk = (ht + 1) % 7;
      const ushort_t* Ah_ = nh ? A2 : A1;
      const float* w_ = nh ? w2 : w1;
      #pragma unroll
      for (int r = 0; r < 2; r++)
        GLD_LDS16(Ah_ + ((size_t)qi * 128 + r * 64 + lane) * KP + 32 * nk + wv * 8,
                  As[(ht + 1) & 1] + wv * APLANE + r * 1024);
      int r0 = idxr0[nk], r1 = idxr1[nk];
      #pragma unroll
      for (int u = 0; u < 2; u++) {
        pw[0][u] = *(const float4*)(w_ + (size_t)r0 * C_ + cbase + (cq + 4 * u) * 4);
        pw[1][u] = *(const float4*)(w_ + (size_t)r1 * C_ + cbase + (cq + 4 * u) * 4);
      }
    }

    // MFMA phase: LDS only
    const char* ab = As[ht & 1];
    bf16x8 bfv[2];
    #pragma unroll
    for (int u = 0; u < 2; u++)
      bfv[u] = *(const bf16x8*)&Ws[wv * 32 + 16 * u + l15][8 * quad];
    #pragma unroll
    for (int mt = 0; mt < 8; mt++) {
      bf16x8 a = *(const bf16x8*)(ab + quad * APLANE + (16 * mt + l15) * 16);
      acc[mt][0] = __builtin_amdgcn_mfma_f32_16x16x32_bf16(a, bfv[0], acc[mt][0], 0, 0, 0);
      acc[mt][1] = __builtin_amdgcn_mfma_f32_16x16x32_bf16(a, bfv[1], acc[mt][1], 0, 0, 0);
    }
  }

  #pragma unroll
  for (int u = 0; u < 2; u++) {
    const int c = ct * 128 + 32 * wv + 16 * u + l15;
    #pragma unroll
    for (int mt = 0; mt < 8; mt++)
      #pragma unroll
      for (int r = 0; r < 4; r++) {
        int m = 16 * mt + 4 * quad + r;
        out[((size_t)m * L_ + 1 + qi) * C_ + c] = acc[mt][u][r];
      }
  }
  if (qi == 0) {
    #pragma unroll
    for (int u = 0; u < 2; u++) {
      const int c = ct * 128 + 32 * wv + 16 * u + l15;
      #pragma unroll
      for (int mt = 0; mt < 8; mt++)
        #pragma unroll
        for (int r = 0; r < 4; r++) {
          int m = 16 * mt + 4 * quad + r;
          out[(size_t)m * L_ * C_ + c] = 0.f;
        }
    }
  }
}

extern "C" void kernel_launch(void* const* d_in, const int* in_sizes, int n_in,
                              void* d_out, int out_size, void* d_ws, size_t ws_size,
                              hipStream_t stream) {
  const float* q  = (const float*)d_in[0];
  const float* k  = (const float*)d_in[1];
  const float* w1 = (const float*)d_in[2];
  const float* w2 = (const float*)d_in[3];
  const int* idx  = (const int*)d_in[4];
  float* out = (float*)d_out;

  const size_t plane_tot = (size_t)(N_ * T_) * H_ * ENT;   // uint4 entries
  uint4* qb = (uint4*)d_ws;
  uint4* kb = qb + plane_tot;
  ushort_t* A1 = (ushort_t*)(kb + plane_tot);
  size_t Aelems = (size_t)Q_ * (N_ * T_) * KP;
  ushort_t* A2 = A1 + Aelems;

  // zero A buffers: covers k-pad cols and the empty t-slots
  hipMemsetAsync(A1, 0, Aelems * 2 * sizeof(ushort_t), stream);

  convert_kernel<<<dim3(N_ * T_, 7, 2), 256, 0, stream>>>(q, k, qb, kb);
  attn_kernel<<<dim3(896), 256, 0, stream>>>(qb, kb, A1, A2);
  mix_kernel<<<dim3(6, Q_), 256, 0, stream>>>(A1, A2, w1, w2, idx, out);
}